// Round 5
// baseline (159.895 us; speedup 1.0000x reference)
//
#include <hip/hip_runtime.h>

// GMELoss3D: fused 3D Sobel edge-magnitude MSE on [2,2,128,128,128] fp32 volumes.
// R5: barrier-free / LDS-free redesign. One wave owns a 64-wide x-segment at a
// fixed y, marching z. x-neighbor exchange via __shfl (in-register); y-neighbors
// by loading 3 rows per plane (L2/L3 absorb the 3x reuse); the one interior
// x-junction column comes from a predicated +/-1-element load on the edge lane.
// Software pipeline: issue plane z+1 loads -> compute plane z -> channel-sum
// arrivals (waitcnt after compute). No __syncthreads anywhere.
//
// Separable decomposition (s=[1,2,1], d=[-1,0,1], e=[1,1,1]), reordered:
// per column x compute ys=s_y v, yd=d_y v, ye=e_y v from 3 rows; then
//   C0=s_y d_x = ysR-ysL        C1=d_y s_x = ydL+2yd+ydR
//   C2=s_y s_x = ysL+2ys+ysR    C3=e_y d_x = yeR-yeL
//   C4=d_y e_x = ydL+yd+ydR     C5=e_y s_x = yeL+2ye+yeR
//   C6=s_y e_x = ysL+ys+ysR
// z-combines unchanged from the verified R2 kernel. Signs irrelevant (squared).

namespace {

constexpr int YX = 128 * 128;
constexpr ptrdiff_t CS = (ptrdiff_t)128 * YX;    // channel stride
constexpr int ZC = 16;                           // z-planes per wave
constexpr float INV_N = 1.0f / 4194304.0f;

// half edge magnitude (mag / C, C=2) from 3 planes' combos (a=z-1, b=z, c=z+1)
__device__ __forceinline__ float edge_mag_half(const float* __restrict__ Ca,
                                               const float* __restrict__ Cb,
                                               const float* __restrict__ Cc) {
  const float g1  = __builtin_fmaf(2.0f, Cb[0], Ca[0] + Cc[0]);   // Sx
  const float g2  = __builtin_fmaf(2.0f, Cb[1], Ca[1] + Cc[1]);   // Sy
  const float g3  = Cc[2] - Ca[2];                                // Sz
  const float Azx = __builtin_fmaf(2.0f, Cb[3], Ca[3] + Cc[3]);   // s_z e_y d_x
  const float Azy = __builtin_fmaf(2.0f, Cb[4], Ca[4] + Cc[4]);   // s_z d_y e_x
  const float Axz = Cc[5] - Ca[5];                                // d_z e_y s_x
  const float Axy = g2 - Cb[1];                                   // e_z d_y s_x
  const float Ayx = g1 - Cb[0];                                   // e_z s_y d_x
  const float Ayz = Cc[6] - Ca[6];                                // d_z s_y e_x
  const float g4 = Azx - Azy, g5 = Azx + Azy;                     // Sd11, Sd12
  const float g6 = Axz - Axy, g7 = Axz + Axy;                     // Sd21, Sd22
  const float g8 = Ayx - Ayz, g9 = Ayx + Ayz;                     // Sd31, Sd32
  float s = __builtin_fmaf(g1, g1, 1e-12f);
  s = __builtin_fmaf(g2, g2, s); s = __builtin_fmaf(g3, g3, s);
  s = __builtin_fmaf(g4, g4, s); s = __builtin_fmaf(g5, g5, s);
  s = __builtin_fmaf(g6, g6, s); s = __builtin_fmaf(g7, g7, s);
  s = __builtin_fmaf(g8, g8, s); s = __builtin_fmaf(g9, g9, s);
  return 0.5f * sqrtf(s);
}

// 7 plane-combos from channel-summed column triple s[3] and halo triple h[3]
__device__ __forceinline__ void combos7(const float* __restrict__ s,
                                        const float* __restrict__ h,
                                        bool l0, bool l63, int seg,
                                        float* __restrict__ C) {
  const float t  = s[0] + s[2];
  const float ys = __builtin_fmaf(2.0f, s[1], t);
  const float ye = t + s[1];
  const float yd = s[2] - s[0];
  const float th  = h[0] + h[2];
  const float hys = __builtin_fmaf(2.0f, h[1], th);
  const float hye = th + h[1];
  const float hyd = h[2] - h[0];
  float ysL = __shfl_up(ys, 1),  ydL = __shfl_up(yd, 1),  yeL = __shfl_up(ye, 1);
  float ysR = __shfl_down(ys, 1), ydR = __shfl_down(yd, 1), yeR = __shfl_down(ye, 1);
  // seg0: lane0 left = volume boundary (0), lane63 right = halo column
  // seg1: lane0 left = halo column,        lane63 right = volume boundary (0)
  const float eLs = seg ? hys : 0.0f, eLd = seg ? hyd : 0.0f, eLe = seg ? hye : 0.0f;
  const float eRs = seg ? 0.0f : hys, eRd = seg ? 0.0f : hyd, eRe = seg ? 0.0f : hye;
  ysL = l0 ? eLs : ysL;  ydL = l0 ? eLd : ydL;  yeL = l0 ? eLe : yeL;
  ysR = l63 ? eRs : ysR; ydR = l63 ? eRd : ydR; yeR = l63 ? eRe : yeR;
  C[0] = ysR - ysL;
  const float tds = ydL + ydR;
  C[1] = __builtin_fmaf(2.0f, yd, tds);
  C[4] = tds + yd;
  const float tss = ysL + ysR;
  C[2] = __builtin_fmaf(2.0f, ys, tss);
  C[6] = tss + ys;
  C[3] = yeR - yeL;
  const float tes = yeL + yeR;
  C[5] = __builtin_fmaf(2.0f, ye, tes);
}

__global__ __launch_bounds__(64)
void gme_loss_kernel(const float* __restrict__ y,
                     const float* __restrict__ yp,
                     float* __restrict__ out) {
  const int lane = threadIdx.x;                 // x within segment
  const int yy   = blockIdx.x;                  // row (W axis)
  const int seg  = blockIdx.y >> 3;             // x-segment: 0 -> x 0..63, 1 -> 64..127
  const int z0   = (blockIdx.y & 7) * ZC;       // z-chunk base
  const int b    = blockIdx.z;                  // batch
  const int px   = seg * 64 + lane;
  const bool l0 = (lane == 0), l63 = (lane == 63);
  const bool isEdge = seg ? l0 : l63;           // lane owning the junction halo
  const ptrdiff_t hd = seg ? -1 : 1;            // halo column offset (elements)
  const float w0 = (yy > 0)   ? 1.0f : 0.0f;    // y=0 boundary -> zero row
  const float w2 = (yy < 127) ? 1.0f : 0.0f;
  const int r0 = (yy > 0) ? yy - 1 : 0;
  const int r2 = (yy < 127) ? yy + 1 : 127;

  const float* Yb = y  + (ptrdiff_t)b * 2 * CS;
  const float* Pb = yp + (ptrdiff_t)b * 2 * CS;
  const ptrdiff_t o0 = (ptrdiff_t)r0 * 128 + px;
  const ptrdiff_t o1 = (ptrdiff_t)yy * 128 + px;
  const ptrdiff_t o2 = (ptrdiff_t)r2 * 128 + px;

  float ar[12];                 // in-flight raw loads: [vol*6 + row*2 + ch]
  float hr[12];                 // in-flight halo raws (edge lane only; others stay 0)
#pragma unroll
  for (int j = 0; j < 12; ++j) { ar[j] = 0.0f; hr[j] = 0.0f; }

  float sY[3], hY[3], sP[3], hP[3];   // channel-summed current-plane columns

  auto issue = [&](int zl) {
    if ((unsigned)zl < 128u) {
      const float* Yz = Yb + (ptrdiff_t)zl * YX;
      const float* Pz = Pb + (ptrdiff_t)zl * YX;
      ar[0] = Yz[o0]; ar[1]  = Yz[o0 + CS];
      ar[2] = Yz[o1]; ar[3]  = Yz[o1 + CS];
      ar[4] = Yz[o2]; ar[5]  = Yz[o2 + CS];
      ar[6] = Pz[o0]; ar[7]  = Pz[o0 + CS];
      ar[8] = Pz[o1]; ar[9]  = Pz[o1 + CS];
      ar[10] = Pz[o2]; ar[11] = Pz[o2 + CS];
      if (isEdge) {               // junction column, own address +/- 1 element
        hr[0] = Yz[o0 + hd]; hr[1]  = Yz[o0 + CS + hd];
        hr[2] = Yz[o1 + hd]; hr[3]  = Yz[o1 + CS + hd];
        hr[4] = Yz[o2 + hd]; hr[5]  = Yz[o2 + CS + hd];
        hr[6] = Pz[o0 + hd]; hr[7]  = Pz[o0 + CS + hd];
        hr[8] = Pz[o1 + hd]; hr[9]  = Pz[o1 + CS + hd];
        hr[10] = Pz[o2 + hd]; hr[11] = Pz[o2 + CS + hd];
      }
    } else {
#pragma unroll
      for (int j = 0; j < 12; ++j) { ar[j] = 0.0f; hr[j] = 0.0f; }
    }
  };
  auto reduceb = [&]() {          // channel sums + y-boundary masking
    sY[0] = (ar[0] + ar[1]) * w0;  sY[1] = ar[2] + ar[3];  sY[2] = (ar[4] + ar[5]) * w2;
    sP[0] = (ar[6] + ar[7]) * w0;  sP[1] = ar[8] + ar[9];  sP[2] = (ar[10] + ar[11]) * w2;
    hY[0] = (hr[0] + hr[1]) * w0;  hY[1] = hr[2] + hr[3];  hY[2] = (hr[4] + hr[5]) * w2;
    hP[0] = (hr[6] + hr[7]) * w0;  hP[1] = hr[8] + hr[9];  hP[2] = (hr[10] + hr[11]) * w2;
  };

  float KY[3][7], KP[3][7];
  float acc = 0.0f;

  issue(z0 - 1);                  // chunk 0: z=-1 -> zeros
  reduceb();

#pragma unroll 6
  for (int i = 0; i < ZC + 2; ++i) {           // 18 steps, plane zc = z0-1+i
    const int zl = (i < ZC + 1) ? (z0 + i) : 128;   // next plane (skip useless last)
    issue(zl);                                  // loads in flight during compute
    combos7(sY, hY, l0, l63, seg, KY[i % 3]);
    combos7(sP, hP, l0, l63, seg, KP[i % 3]);
    if (i >= 2) {                               // emit output plane z0-2+i
      const float my = edge_mag_half(KY[(i + 1) % 3], KY[(i + 2) % 3], KY[i % 3]);
      const float mp = edge_mag_half(KP[(i + 1) % 3], KP[(i + 2) % 3], KP[i % 3]);
      const float d = my - mp;
      acc = __builtin_fmaf(d, d, acc);
    }
    reduceb();                                  // waitcnt lands here, after compute
  }

  // ---- wave reduction, one atomic per wave ----
#pragma unroll
  for (int off = 32; off > 0; off >>= 1) acc += __shfl_down(acc, off);
  if (lane == 0) atomicAdd(out, acc * INV_N);
}

}  // namespace

extern "C" void kernel_launch(void* const* d_in, const int* in_sizes, int n_in,
                              void* d_out, int out_size, void* d_ws, size_t ws_size,
                              hipStream_t stream) {
  const float* y  = (const float*)d_in[0];
  const float* yp = (const float*)d_in[1];
  float* out = (float*)d_out;

  // d_out is poisoned before every launch: zero via memset node (graph-capturable)
  hipMemsetAsync(out, 0, sizeof(float), stream);

  dim3 block(64, 1, 1);                         // one wave per block
  dim3 grid(128,                                // y rows
            16,                                 // 2 x-segments * 8 z-chunks
            2);                                 // batch
  gme_loss_kernel<<<grid, block, 0, stream>>>(y, yp, out);
}

// Round 6
// 123.369 us; speedup vs baseline: 1.2961x; 1.2961x over previous
//
#include <hip/hip_runtime.h>

// GMELoss3D: fused 3D Sobel edge-magnitude MSE on [2,2,128,128,128] fp32 volumes.
// R6: R5's barrier-free wave-per-row dataflow, repackaged:
//   - 4 waves / 256-thread block (R5's 1-wave blocks gave 18% occupancy),
//     each wave owns one y-row; NO __syncthreads in the z-loop.
//   - distance-2 software pipeline for the 12 main loads (double-buffered raw
//     regs); halo loads distance-1, issued before the next main batch so the
//     per-step consume-wait is vmcnt(12), never vmcnt(0).
//   - x-neighbors via __shfl; y-neighbors via 3-row loads (L1/L2 absorb 3x,
//     proven R5: FETCH stayed ~109 MB); x-junction column via predicated
//     +/-1-element loads on the edge lane.
//
// Separable decomposition (s=[1,2,1], d=[-1,0,1], e=[1,1,1]); per column:
// ys,yd,ye from 3 rows, then x-combines via shuffles, then z-combines from
// mod-3 rotated per-plane combos. Verified exact (absmax 0.0) in R5.

namespace {

constexpr int YX = 128 * 128;
constexpr ptrdiff_t CS = (ptrdiff_t)128 * YX;    // channel stride
constexpr int ZC = 16;                           // z-planes per wave
constexpr float INV_N = 1.0f / 4194304.0f;

__device__ __forceinline__ float edge_mag_half(const float* __restrict__ Ca,
                                               const float* __restrict__ Cb,
                                               const float* __restrict__ Cc) {
  const float g1  = __builtin_fmaf(2.0f, Cb[0], Ca[0] + Cc[0]);   // Sx
  const float g2  = __builtin_fmaf(2.0f, Cb[1], Ca[1] + Cc[1]);   // Sy
  const float g3  = Cc[2] - Ca[2];                                // Sz
  const float Azx = __builtin_fmaf(2.0f, Cb[3], Ca[3] + Cc[3]);   // s_z e_y d_x
  const float Azy = __builtin_fmaf(2.0f, Cb[4], Ca[4] + Cc[4]);   // s_z d_y e_x
  const float Axz = Cc[5] - Ca[5];                                // d_z e_y s_x
  const float Axy = g2 - Cb[1];                                   // e_z d_y s_x
  const float Ayx = g1 - Cb[0];                                   // e_z s_y d_x
  const float Ayz = Cc[6] - Ca[6];                                // d_z s_y e_x
  const float g4 = Azx - Azy, g5 = Azx + Azy;                     // Sd11, Sd12
  const float g6 = Axz - Axy, g7 = Axz + Axy;                     // Sd21, Sd22
  const float g8 = Ayx - Ayz, g9 = Ayx + Ayz;                     // Sd31, Sd32
  float s = __builtin_fmaf(g1, g1, 1e-12f);
  s = __builtin_fmaf(g2, g2, s); s = __builtin_fmaf(g3, g3, s);
  s = __builtin_fmaf(g4, g4, s); s = __builtin_fmaf(g5, g5, s);
  s = __builtin_fmaf(g6, g6, s); s = __builtin_fmaf(g7, g7, s);
  s = __builtin_fmaf(g8, g8, s); s = __builtin_fmaf(g9, g9, s);
  return 0.5f * sqrtf(s);
}

// 7 plane-combos from channel-summed column triple s[3] and halo triple h[3]
__device__ __forceinline__ void combos7(const float* __restrict__ s,
                                        const float* __restrict__ h,
                                        bool l0, bool l63, int seg,
                                        float* __restrict__ C) {
  const float t  = s[0] + s[2];
  const float ys = __builtin_fmaf(2.0f, s[1], t);
  const float ye = t + s[1];
  const float yd = s[2] - s[0];
  const float th  = h[0] + h[2];
  const float hys = __builtin_fmaf(2.0f, h[1], th);
  const float hye = th + h[1];
  const float hyd = h[2] - h[0];
  float ysL = __shfl_up(ys, 1),  ydL = __shfl_up(yd, 1),  yeL = __shfl_up(ye, 1);
  float ysR = __shfl_down(ys, 1), ydR = __shfl_down(yd, 1), yeR = __shfl_down(ye, 1);
  const float eLs = seg ? hys : 0.0f, eLd = seg ? hyd : 0.0f, eLe = seg ? hye : 0.0f;
  const float eRs = seg ? 0.0f : hys, eRd = seg ? 0.0f : hyd, eRe = seg ? 0.0f : hye;
  ysL = l0 ? eLs : ysL;  ydL = l0 ? eLd : ydL;  yeL = l0 ? eLe : yeL;
  ysR = l63 ? eRs : ysR; ydR = l63 ? eRd : ydR; yeR = l63 ? eRe : yeR;
  C[0] = ysR - ysL;
  const float tds = ydL + ydR;
  C[1] = __builtin_fmaf(2.0f, yd, tds);
  C[4] = tds + yd;
  const float tss = ysL + ysR;
  C[2] = __builtin_fmaf(2.0f, ys, tss);
  C[6] = tss + ys;
  C[3] = yeR - yeL;
  const float tes = yeL + yeR;
  C[5] = __builtin_fmaf(2.0f, ye, tes);
}

__global__ __launch_bounds__(256)
void gme_loss_kernel(const float* __restrict__ y,
                     const float* __restrict__ yp,
                     float* __restrict__ out) {
  const int tid  = threadIdx.x;
  const int lane = tid & 63;
  const int wv   = tid >> 6;                    // 0..3, wave id in block
  const int yy   = blockIdx.x * 4 + wv;         // this wave's row (W axis)
  const int seg  = blockIdx.y >> 3;             // x-segment: 0 -> x 0..63, 1 -> 64..127
  const int z0   = (blockIdx.y & 7) * ZC;       // z-chunk base
  const int b    = blockIdx.z;                  // batch
  const int px   = seg * 64 + lane;
  const bool l0 = (lane == 0), l63 = (lane == 63);
  const bool isEdge = seg ? l0 : l63;           // lane owning the junction halo
  const ptrdiff_t hd = seg ? -1 : 1;            // halo column offset (elements)
  const float w0 = (yy > 0)   ? 1.0f : 0.0f;    // y boundary masks
  const float w2 = (yy < 127) ? 1.0f : 0.0f;
  const int r0 = (yy > 0) ? yy - 1 : 0;
  const int r2 = (yy < 127) ? yy + 1 : 127;

  const float* Yb = y  + (ptrdiff_t)b * 2 * CS;
  const float* Pb = yp + (ptrdiff_t)b * 2 * CS;
  const ptrdiff_t o0 = (ptrdiff_t)r0 * 128 + px;
  const ptrdiff_t o1 = (ptrdiff_t)yy * 128 + px;
  const ptrdiff_t o2 = (ptrdiff_t)r2 * 128 + px;

  float arA[12], arB[12], hr[12];
#pragma unroll
  for (int j = 0; j < 12; ++j) { arA[j] = 0.f; arB[j] = 0.f; hr[j] = 0.f; }

  auto issue_ar = [&](int zl, float* __restrict__ a) {
    if ((unsigned)zl < 128u) {
      const float* Yz = Yb + (ptrdiff_t)zl * YX;
      const float* Pz = Pb + (ptrdiff_t)zl * YX;
      a[0]  = Yz[o0]; a[1]  = Yz[o0 + CS];
      a[2]  = Yz[o1]; a[3]  = Yz[o1 + CS];
      a[4]  = Yz[o2]; a[5]  = Yz[o2 + CS];
      a[6]  = Pz[o0]; a[7]  = Pz[o0 + CS];
      a[8]  = Pz[o1]; a[9]  = Pz[o1 + CS];
      a[10] = Pz[o2]; a[11] = Pz[o2 + CS];
    } else {
#pragma unroll
      for (int j = 0; j < 12; ++j) a[j] = 0.0f;
    }
  };
  auto issue_hr = [&](int zl) {
    if ((unsigned)zl < 128u) {
      if (isEdge) {
        const float* Yz = Yb + (ptrdiff_t)zl * YX;
        const float* Pz = Pb + (ptrdiff_t)zl * YX;
        hr[0]  = Yz[o0 + hd]; hr[1]  = Yz[o0 + CS + hd];
        hr[2]  = Yz[o1 + hd]; hr[3]  = Yz[o1 + CS + hd];
        hr[4]  = Yz[o2 + hd]; hr[5]  = Yz[o2 + CS + hd];
        hr[6]  = Pz[o0 + hd]; hr[7]  = Pz[o0 + CS + hd];
        hr[8]  = Pz[o1 + hd]; hr[9]  = Pz[o1 + CS + hd];
        hr[10] = Pz[o2 + hd]; hr[11] = Pz[o2 + CS + hd];
      }
    } else {
#pragma unroll
      for (int j = 0; j < 12; ++j) hr[j] = 0.0f;
    }
  };

  float sY[3], hY[3], sP[3], hP[3];
  auto consume = [&](const float* __restrict__ a) {
    sY[0] = (a[0] + a[1])  * w0;  sY[1] = a[2] + a[3];  sY[2] = (a[4] + a[5])  * w2;
    sP[0] = (a[6] + a[7])  * w0;  sP[1] = a[8] + a[9];  sP[2] = (a[10] + a[11]) * w2;
    hY[0] = (hr[0] + hr[1]) * w0; hY[1] = hr[2] + hr[3]; hY[2] = (hr[4] + hr[5]) * w2;
    hP[0] = (hr[6] + hr[7]) * w0; hP[1] = hr[8] + hr[9]; hP[2] = (hr[10] + hr[11]) * w2;
  };

  float KY[3][7], KP[3][7];
  float acc = 0.0f;

  // prologue: ar at distance 2, hr at distance 1
  issue_ar(z0 - 1, arA);          // consumed at i=0
  issue_hr(z0 - 1);               // consumed at i=0
  issue_ar(z0, arB);              // consumed at i=1 (stays in flight across step 0)

#pragma unroll 6
  for (int i = 0; i < ZC + 2; ++i) {           // 18 steps, plane zc = z0-1+i
    const int zc = z0 - 1 + i;
    consume((i & 1) ? arB : arA);               // waits ar(zc)+hr(zc); ar(zc+1) stays in flight
    const int zl_hr = (i <= ZC)     ? (zc + 1) : 128;   // consumed at i+1
    const int zl_ar = (i <= ZC - 1) ? (zc + 2) : 128;   // consumed at i+2
    issue_hr(zl_hr);                            // issue halo first (older in queue)
    issue_ar(zl_ar, (i & 1) ? arB : arA);       // then main batch for zc+2
    combos7(sY, hY, l0, l63, seg, KY[i % 3]);
    combos7(sP, hP, l0, l63, seg, KP[i % 3]);
    if (i >= 2) {                               // emit output plane zc-1
      const float my = edge_mag_half(KY[(i + 1) % 3], KY[(i + 2) % 3], KY[i % 3]);
      const float mp = edge_mag_half(KP[(i + 1) % 3], KP[(i + 2) % 3], KP[i % 3]);
      const float d = my - mp;
      acc = __builtin_fmaf(d, d, acc);
    }
  }

  // ---- per-wave reduce, then one atomic per block ----
#pragma unroll
  for (int off = 32; off > 0; off >>= 1) acc += __shfl_down(acc, off);
  __shared__ float red[4];
  if (lane == 0) red[wv] = acc;
  __syncthreads();
  if (tid == 0) atomicAdd(out, (red[0] + red[1] + red[2] + red[3]) * INV_N);
}

}  // namespace

extern "C" void kernel_launch(void* const* d_in, const int* in_sizes, int n_in,
                              void* d_out, int out_size, void* d_ws, size_t ws_size,
                              hipStream_t stream) {
  const float* y  = (const float*)d_in[0];
  const float* yp = (const float*)d_in[1];
  float* out = (float*)d_out;

  // d_out is poisoned before every launch: zero via memset node (graph-capturable)
  hipMemsetAsync(out, 0, sizeof(float), stream);

  dim3 block(256, 1, 1);                        // 4 waves, each owns one y-row
  dim3 grid(32,                                 // 128 rows / 4 per block
            16,                                 // 2 x-segments * 8 z-chunks
            2);                                 // batch
  gme_loss_kernel<<<grid, block, 0, stream>>>(y, yp, out);
}